// Round 1
// baseline (9366.739 us; speedup 1.0000x reference)
//
#include <hip/hip_runtime.h>
#include <hip/hip_bf16.h>

// LSTM: B=64, T=512, I=256, H=1024, O=1.
// Persistent cooperative kernel: 256 blocks = 4 batch-groups x 64 unit-groups.
// Each block: 16 batches x 16 hidden units (= 64 gate rows i,f,g,o).
// 8 waves/block K-split the 1280-wide reduction; weights live in VGPRs as
// bf16 MFMA B-fragments; h broadcast via double-buffered global bf16 buffer
// with a per-batch-group device-scope barrier each timestep.

typedef __bf16 bf16_t;
typedef bf16_t b16x8 __attribute__((ext_vector_type(8)));
typedef short  s16x8 __attribute__((ext_vector_type(8)));
typedef float  f32x4 __attribute__((ext_vector_type(4)));

#define TQ 512
#define IQ 256
#define HQ 1024

union U8 { b16x8 b; s16x8 s; unsigned short u[8]; };

__device__ __forceinline__ float bf2f(unsigned short s) {
    return __uint_as_float(((unsigned)s) << 16);
}
__device__ __forceinline__ unsigned short f2bf(float f) {
    unsigned u = __float_as_uint(f);
    u += 0x7fff + ((u >> 16) & 1);   // RNE
    return (unsigned short)(u >> 16);
}
__device__ __forceinline__ b16x8 cvt84(float4 a, float4 b) {
    U8 r;
    r.u[0] = f2bf(a.x); r.u[1] = f2bf(a.y); r.u[2] = f2bf(a.z); r.u[3] = f2bf(a.w);
    r.u[4] = f2bf(b.x); r.u[5] = f2bf(b.y); r.u[6] = f2bf(b.z); r.u[7] = f2bf(b.w);
    return r.b;
}
__device__ __forceinline__ float sigm(float x) {
    return 1.f / (1.f + __expf(-x));
}
__device__ __forceinline__ float tanh_f(float v) {
    float x = fminf(fmaxf(v, -15.f), 15.f);
    float e = __expf(2.f * x);
    return (e - 1.f) / (e + 1.f);
}

__launch_bounds__(512, 2)
__global__ void lstm_persist(const float* __restrict__ x,
                             const float* __restrict__ Wih,
                             const float* __restrict__ Whh,
                             const float* __restrict__ bih,
                             const float* __restrict__ bhh,
                             const float* __restrict__ fcW,
                             const float* __restrict__ fcb,
                             float* __restrict__ out,
                             unsigned short* __restrict__ hbuf, // [2][4][16][1024] bf16
                             unsigned int* __restrict__ bar)    // [4]
{
    __shared__ float red[8 * 4 * 64 * 4];  // 32KB: per-wave partial C tiles
    __shared__ float gbuf[4 * 16 * 16];    // 4KB: summed gates [gate][b][u]
    __shared__ float cst[256];             // cell state [b][u]
    __shared__ float bias_s[64];           // b_ih + b_hh for our 64 gate rows

    const int tid  = threadIdx.x;
    const int w    = tid >> 6;        // wave 0..7
    const int lane = tid & 63;
    const int bid  = blockIdx.x;
    const int bg   = bid & 3;         // batch group (16 batches)
    const int ug   = bid >> 2;        // unit group (16 hidden units)

    const int l16  = lane & 15;
    const int quad = lane >> 4;

    if (tid < 64) {
        int g = tid >> 4, u = tid & 15;
        int gr = g * HQ + ug * 16 + u;
        bias_s[tid] = bih[gr] + bhh[gr];
    }
    if (tid < 256) cst[tid] = 0.f;

    // ---- one-time: load weight fragments into registers (bf16) ----
    // B^T-fragment: lane holds W[row = n_base + (lane&15)][k0 + quad*8 + j]
    b16x8 wih[4];        // x part: this wave's x-kstep (cols w*32..w*32+32)
    b16x8 whh[4][4];     // h part: ksteps (4w+j), per gate
    {
        const int koff = quad * 8;
        #pragma unroll
        for (int g = 0; g < 4; ++g) {
            int row = g * HQ + ug * 16 + l16;
            const float* p = Wih + (size_t)row * IQ + w * 32 + koff;
            float4 a = *(const float4*)p;
            float4 b = *(const float4*)(p + 4);
            wih[g] = cvt84(a, b);
            #pragma unroll
            for (int j = 0; j < 4; ++j) {
                int k0 = (w * 4 + j) * 32 + koff;
                const float* q = Whh + (size_t)row * HQ + k0;
                float4 c = *(const float4*)q;
                float4 d = *(const float4*)(q + 4);
                whh[j][g] = cvt84(c, d);
            }
        }
    }
    __syncthreads();

    const int n_tile = w >> 1;   // reduction assignment: gate tile
    const int hhalf  = w & 1;    // which reg-pair of the C tile

    for (int t = 0; t < TQ; ++t) {
        const int p = t & 1;
        const unsigned short* hread = hbuf + ((size_t)p * 4 + bg) * (16 * HQ);

        // ---- A fragments (direct global -> VGPR) ----
        const float* xp = x + ((size_t)(bg * 16 + l16) * TQ + t) * IQ + w * 32 + quad * 8;
        float4 xa = *(const float4*)xp;
        float4 xb = *(const float4*)(xp + 4);
        b16x8 ax = cvt84(xa, xb);

        b16x8 ah[4];
        #pragma unroll
        for (int j = 0; j < 4; ++j) {
            const unsigned short* hp = hread + (size_t)l16 * HQ + (w * 4 + j) * 32 + quad * 8;
            U8 tmp; tmp.s = *(const s16x8*)hp;
            ah[j] = tmp.b;
        }

        // ---- MFMA: 4 gate chains, K-slice of this wave ----
        f32x4 acc[4];
        #pragma unroll
        for (int g = 0; g < 4; ++g) {
            f32x4 z = {0.f, 0.f, 0.f, 0.f};
            acc[g] = __builtin_amdgcn_mfma_f32_16x16x32_bf16(ax, wih[g], z, 0, 0, 0);
        }
        #pragma unroll
        for (int j = 0; j < 4; ++j) {
            #pragma unroll
            for (int g = 0; g < 4; ++g)
                acc[g] = __builtin_amdgcn_mfma_f32_16x16x32_bf16(ah[j], whh[j][g], acc[g], 0, 0, 0);
        }

        // ---- write per-wave partials ----
        #pragma unroll
        for (int g = 0; g < 4; ++g)
            *(f32x4*)&red[((w * 4 + g) * 64 + lane) * 4] = acc[g];
        __syncthreads();

        // ---- 8-way K reduction + bias ----
        {
            float s0 = 0.f, s1 = 0.f;
            #pragma unroll
            for (int ww = 0; ww < 8; ++ww) {
                const float* rp = &red[((ww * 4 + n_tile) * 64 + lane) * 4 + hhalf * 2];
                s0 += rp[0];
                s1 += rp[1];
            }
            float bv = bias_s[n_tile * 16 + l16];
            int brow = quad * 4 + hhalf * 2;   // C layout: row=(lane>>4)*4+reg, col=lane&15
            gbuf[(n_tile * 16 + brow) * 16 + l16]     = s0 + bv;
            gbuf[(n_tile * 16 + brow + 1) * 16 + l16] = s1 + bv;
        }
        __syncthreads();

        // ---- elementwise LSTM update, write h (bf16) ----
        if (tid < 256) {
            int b = tid >> 4, u = tid & 15;
            float gi = gbuf[(0 * 16 + b) * 16 + u];
            float gf = gbuf[(1 * 16 + b) * 16 + u];
            float gg = gbuf[(2 * 16 + b) * 16 + u];
            float go = gbuf[(3 * 16 + b) * 16 + u];
            float i_s = sigm(gi);
            float f_s = sigm(gf);
            float g_t = tanh_f(gg);
            float o_s = sigm(go);
            float c = f_s * cst[tid] + i_s * g_t;
            cst[tid] = c;
            float h = o_s * tanh_f(c);
            unsigned short* hw = hbuf + (((size_t)(p ^ 1) * 4 + bg) * 16 + b) * HQ + ug * 16 + u;
            *hw = f2bf(h);
        }
        __syncthreads();   // drains the h stores (s_barrier implies vmcnt(0))

        // ---- device-scope barrier within the batch group (64 blocks) ----
        if (tid == 0) {
            __threadfence();                      // release: h visible agent-wide
            atomicAdd(&bar[bg], 1u);
            unsigned target = 64u * (unsigned)(t + 1);
            while (__hip_atomic_load(&bar[bg], __ATOMIC_RELAXED,
                                     __HIP_MEMORY_SCOPE_AGENT) < target)
                __builtin_amdgcn_s_sleep(2);
            __threadfence();                      // acquire: invalidate caches
        }
        __syncthreads();
    }

    // ---- final projection: out = tanh(h_T) @ fcW^T + fcb (blocks 0..3) ----
    if (bid < 4) {
        const unsigned short* hl = hbuf + (size_t)bg * (16 * HQ); // parity: T even -> buf0
        float fb = fcb[0];
        #pragma unroll
        for (int r = 0; r < 2; ++r) {
            int b = w * 2 + r;
            float s = 0.f;
            #pragma unroll
            for (int j = 0; j < 16; ++j) {
                int u = j * 64 + lane;
                s += tanh_f(bf2f(hl[b * HQ + u])) * fcW[u];
            }
            #pragma unroll
            for (int off = 32; off > 0; off >>= 1)
                s += __shfl_down(s, off);
            if (lane == 0) out[bg * 16 + b] = s + fb;
        }
    }
}

extern "C" void kernel_launch(void* const* d_in, const int* in_sizes, int n_in,
                              void* d_out, int out_size, void* d_ws, size_t ws_size,
                              hipStream_t stream) {
    (void)in_sizes; (void)n_in; (void)out_size; (void)ws_size;
    const float* x   = (const float*)d_in[0];
    const float* Wih = (const float*)d_in[1];
    const float* Whh = (const float*)d_in[2];
    const float* bih = (const float*)d_in[3];
    const float* bhh = (const float*)d_in[4];
    const float* fcW = (const float*)d_in[5];
    const float* fcb = (const float*)d_in[6];
    float* out = (float*)d_out;

    unsigned short* hbuf = (unsigned short*)d_ws;                       // 262144 B
    unsigned int*   bar  = (unsigned int*)((char*)d_ws + 262144);       // 16 B

    // zero h buffers + barrier counters (ws is poisoned 0xAA before every launch)
    hipMemsetAsync(d_ws, 0, 262144 + 16, stream);

    void* args[] = { &x, &Wih, &Whh, &bih, &bhh, &fcW, &fcb, &out, &hbuf, &bar };
    hipLaunchCooperativeKernel(reinterpret_cast<void*>(lstm_persist),
                               dim3(256), dim3(512), args, 0, stream);
}

// Round 2
// 3530.683 us; speedup vs baseline: 2.6530x; 2.6530x over previous
//
#include <hip/hip_runtime.h>
#include <hip/hip_bf16.h>

// LSTM: B=64, T=512, I=256, H=1024, O=1.
// Persistent cooperative kernel: 256 blocks = 4 batch-groups x 64 unit-groups.
// Each block: 16 batches x 16 hidden units (= 64 gate rows i,f,g,o).
// 8 waves/block K-split the 1280-wide reduction; weights live in VGPRs as
// bf16 MFMA B-fragments; h broadcast via double-buffered global bf16 buffer.
// R2: all cross-block traffic uses cache-bypassing (sc0 sc1) atomic
// loads/stores -> NO __threadfence (no buffer_wbl2/buffer_inv L2 flushes).

typedef __bf16 bf16_t;
typedef bf16_t b16x8 __attribute__((ext_vector_type(8)));
typedef short  s16x8 __attribute__((ext_vector_type(8)));
typedef float  f32x4 __attribute__((ext_vector_type(4)));

#define TQ 512
#define IQ 256
#define HQ 1024

union U8 { b16x8 b; s16x8 s; unsigned short u[8]; unsigned long long q[2]; };

__device__ __forceinline__ float bf2f(unsigned short s) {
    return __uint_as_float(((unsigned)s) << 16);
}
__device__ __forceinline__ unsigned short f2bf(float f) {
    unsigned u = __float_as_uint(f);
    u += 0x7fff + ((u >> 16) & 1);   // RNE
    return (unsigned short)(u >> 16);
}
__device__ __forceinline__ b16x8 cvt84(float4 a, float4 b) {
    U8 r;
    r.u[0] = f2bf(a.x); r.u[1] = f2bf(a.y); r.u[2] = f2bf(a.z); r.u[3] = f2bf(a.w);
    r.u[4] = f2bf(b.x); r.u[5] = f2bf(b.y); r.u[6] = f2bf(b.z); r.u[7] = f2bf(b.w);
    return r.b;
}
// agent-scope (sc0 sc1) 16B load as 2x8B atomic loads — bypasses the
// non-coherent per-XCD L2 so cross-XCD h values are always current.
__device__ __forceinline__ b16x8 load_h16(const unsigned short* p) {
    U8 r;
    r.q[0] = __hip_atomic_load((const unsigned long long*)p,
                               __ATOMIC_RELAXED, __HIP_MEMORY_SCOPE_AGENT);
    r.q[1] = __hip_atomic_load((const unsigned long long*)(p + 4),
                               __ATOMIC_RELAXED, __HIP_MEMORY_SCOPE_AGENT);
    return r.b;
}
__device__ __forceinline__ float sigm(float x) {
    return 1.f / (1.f + __expf(-x));
}
__device__ __forceinline__ float tanh_f(float v) {
    float x = fminf(fmaxf(v, -15.f), 15.f);
    float e = __expf(2.f * x);
    return (e - 1.f) / (e + 1.f);
}

__launch_bounds__(512, 2)
__global__ void lstm_persist(const float* __restrict__ x,
                             const float* __restrict__ Wih,
                             const float* __restrict__ Whh,
                             const float* __restrict__ bih,
                             const float* __restrict__ bhh,
                             const float* __restrict__ fcW,
                             const float* __restrict__ fcb,
                             float* __restrict__ out,
                             unsigned short* __restrict__ hbuf, // [2][4][16][1024] bf16
                             unsigned int* __restrict__ bar)    // [4*64] (256B stride)
{
    __shared__ float red[8 * 4 * 64 * 4];  // 32KB: per-wave partial C tiles
    __shared__ float gbuf[4 * 16 * 16];    // 4KB: summed gates [gate][b][u]
    __shared__ float cst[256];             // cell state [b][u]
    __shared__ float bias_s[64];           // b_ih + b_hh for our 64 gate rows

    const int tid  = threadIdx.x;
    const int w    = tid >> 6;        // wave 0..7
    const int lane = tid & 63;
    const int bid  = blockIdx.x;
    const int bg   = bid & 3;         // batch group (16 batches)
    const int ug   = bid >> 2;        // unit group (16 hidden units)

    const int l16  = lane & 15;
    const int quad = lane >> 4;

    if (tid < 64) {
        int g = tid >> 4, u = tid & 15;
        int gr = g * HQ + ug * 16 + u;
        bias_s[tid] = bih[gr] + bhh[gr];
    }
    if (tid < 256) cst[tid] = 0.f;

    // ---- one-time: load weight fragments into registers (bf16) ----
    // B^T-fragment: lane holds W[row = n_base + (lane&15)][k0 + quad*8 + j]
    b16x8 wih[4];        // x part: this wave's x-kstep (cols w*32..w*32+32)
    b16x8 whh[4][4];     // h part: ksteps (4w+j), per gate
    {
        const int koff = quad * 8;
        #pragma unroll
        for (int g = 0; g < 4; ++g) {
            int row = g * HQ + ug * 16 + l16;
            const float* p = Wih + (size_t)row * IQ + w * 32 + koff;
            float4 a = *(const float4*)p;
            float4 b = *(const float4*)(p + 4);
            wih[g] = cvt84(a, b);
            #pragma unroll
            for (int j = 0; j < 4; ++j) {
                int k0 = (w * 4 + j) * 32 + koff;
                const float* q = Whh + (size_t)row * HQ + k0;
                float4 c = *(const float4*)q;
                float4 d = *(const float4*)(q + 4);
                whh[j][g] = cvt84(c, d);
            }
        }
    }
    __syncthreads();

    const int n_tile = w >> 1;   // reduction assignment: gate tile
    const int hhalf  = w & 1;    // which reg-pair of the C tile

    unsigned int* mybar = &bar[bg * 64];

    // software-pipelined x load (step 0)
    const float* xbase = x + ((size_t)(bg * 16 + l16) * TQ) * IQ + w * 32 + quad * 8;
    float4 xa = *(const float4*)(xbase);
    float4 xb = *(const float4*)(xbase + 4);

    for (int t = 0; t < TQ; ++t) {
        const int p = t & 1;
        const unsigned short* hread = hbuf + ((size_t)p * 4 + bg) * (16 * HQ);

        // ---- A fragments ----
        b16x8 ax = cvt84(xa, xb);

        b16x8 ah[4];
        #pragma unroll
        for (int j = 0; j < 4; ++j)
            ah[j] = load_h16(hread + (size_t)l16 * HQ + (w * 4 + j) * 32 + quad * 8);

        // ---- MFMA: 4 gate chains, K-slice of this wave ----
        f32x4 acc[4];
        #pragma unroll
        for (int g = 0; g < 4; ++g) {
            f32x4 z = {0.f, 0.f, 0.f, 0.f};
            acc[g] = __builtin_amdgcn_mfma_f32_16x16x32_bf16(ax, wih[g], z, 0, 0, 0);
        }
        #pragma unroll
        for (int j = 0; j < 4; ++j) {
            #pragma unroll
            for (int g = 0; g < 4; ++g)
                acc[g] = __builtin_amdgcn_mfma_f32_16x16x32_bf16(ah[j], whh[j][g], acc[g], 0, 0, 0);
        }

        // ---- write per-wave partials ----
        #pragma unroll
        for (int g = 0; g < 4; ++g)
            *(f32x4*)&red[((w * 4 + g) * 64 + lane) * 4] = acc[g];
        __syncthreads();

        // ---- 8-way K reduction + bias ----
        {
            float s0 = 0.f, s1 = 0.f;
            #pragma unroll
            for (int ww = 0; ww < 8; ++ww) {
                const float* rp = &red[((ww * 4 + n_tile) * 64 + lane) * 4 + hhalf * 2];
                s0 += rp[0];
                s1 += rp[1];
            }
            float bv = bias_s[n_tile * 16 + l16];
            int brow = quad * 4 + hhalf * 2;   // C layout: row=(lane>>4)*4+reg, col=lane&15
            gbuf[(n_tile * 16 + brow) * 16 + l16]     = s0 + bv;
            gbuf[(n_tile * 16 + brow + 1) * 16 + l16] = s1 + bv;
        }
        __syncthreads();

        // ---- elementwise LSTM update, write h (2 units/thread, 4B store) ----
        if (tid < 128) {
            int b = tid >> 3, u0 = (tid & 7) * 2;
            float hh[2];
            #pragma unroll
            for (int k = 0; k < 2; ++k) {
                int u = u0 + k;
                float gi = gbuf[(0 * 16 + b) * 16 + u];
                float gf = gbuf[(1 * 16 + b) * 16 + u];
                float gg = gbuf[(2 * 16 + b) * 16 + u];
                float go = gbuf[(3 * 16 + b) * 16 + u];
                float i_s = sigm(gi);
                float f_s = sigm(gf);
                float g_t = tanh_f(gg);
                float o_s = sigm(go);
                float c = f_s * cst[b * 16 + u] + i_s * g_t;
                cst[b * 16 + u] = c;
                hh[k] = o_s * tanh_f(c);
            }
            unsigned pk = (unsigned)f2bf(hh[0]) | ((unsigned)f2bf(hh[1]) << 16);
            unsigned* hw = (unsigned*)(hbuf +
                (((size_t)(p ^ 1) * 4 + bg) * 16 + b) * HQ + ug * 16 + u0);
            // write-through, device-visible store (sc0 sc1) — no fence needed
            __hip_atomic_store(hw, pk, __ATOMIC_RELAXED, __HIP_MEMORY_SCOPE_AGENT);
        }
        __syncthreads();   // compiler emits s_waitcnt vmcnt(0) before s_barrier:
                           // all h stores of this block are device-visible now

        // ---- arrival (relaxed agent RMW; no wbl2) ----
        if (tid == 0)
            __hip_atomic_fetch_add(mybar, 1u, __ATOMIC_RELAXED,
                                   __HIP_MEMORY_SCOPE_AGENT);

        // prefetch x for t+1 — overlaps the barrier wait
        if (t + 1 < TQ) {
            const float* xp = xbase + (size_t)(t + 1) * IQ;
            xa = *(const float4*)xp;
            xb = *(const float4*)(xp + 4);
        }

        // ---- per-wave poll (uniform branch; all lanes load same addr) ----
        {
            unsigned target = 64u * (unsigned)(t + 1);
            while (__hip_atomic_load(mybar, __ATOMIC_RELAXED,
                                     __HIP_MEMORY_SCOPE_AGENT) < target)
                __builtin_amdgcn_s_sleep(1);
        }
    }

    // ---- final projection: out = tanh(h_T) @ fcW^T + fcb (blocks 0..3) ----
    if (bid < 4) {
        const unsigned short* hl = hbuf + (size_t)bg * (16 * HQ); // T even -> buf0
        float fb = fcb[0];
        #pragma unroll
        for (int r = 0; r < 2; ++r) {
            int b = w * 2 + r;
            float s = 0.f;
            #pragma unroll
            for (int j = 0; j < 16; ++j) {
                int u = j * 64 + lane;
                unsigned short hv = __hip_atomic_load(hl + b * HQ + u,
                                                      __ATOMIC_RELAXED,
                                                      __HIP_MEMORY_SCOPE_AGENT);
                s += tanh_f(bf2f(hv)) * fcW[u];
            }
            #pragma unroll
            for (int off = 32; off > 0; off >>= 1)
                s += __shfl_down(s, off);
            if (lane == 0) out[bg * 16 + b] = s + fb;
        }
    }
}

extern "C" void kernel_launch(void* const* d_in, const int* in_sizes, int n_in,
                              void* d_out, int out_size, void* d_ws, size_t ws_size,
                              hipStream_t stream) {
    (void)in_sizes; (void)n_in; (void)out_size; (void)ws_size;
    const float* x   = (const float*)d_in[0];
    const float* Wih = (const float*)d_in[1];
    const float* Whh = (const float*)d_in[2];
    const float* bih = (const float*)d_in[3];
    const float* bhh = (const float*)d_in[4];
    const float* fcW = (const float*)d_in[5];
    const float* fcb = (const float*)d_in[6];
    float* out = (float*)d_out;

    unsigned short* hbuf = (unsigned short*)d_ws;                       // 262144 B
    unsigned int*   bar  = (unsigned int*)((char*)d_ws + 262144);       // 1024 B

    // zero h buffers + barrier counters (ws is poisoned 0xAA before every launch)
    hipMemsetAsync(d_ws, 0, 262144 + 1024, stream);

    void* args[] = { &x, &Wih, &Whh, &bih, &bhh, &fcW, &fcb, &out, &hbuf, &bar };
    hipLaunchCooperativeKernel(reinterpret_cast<void*>(lstm_persist),
                               dim3(256), dim3(512), args, 0, stream);
}

// Round 3
// 2461.534 us; speedup vs baseline: 3.8052x; 1.4343x over previous
//
#include <hip/hip_runtime.h>
#include <hip/hip_bf16.h>

// LSTM: B=64, T=512, I=256, H=1024, O=1.
// Persistent cooperative kernel: 256 blocks = 4 batch-groups x 64 unit-groups.
// R3: single-poller barrier (tid0 + s_barrier release), x-MFMA moved into the
// barrier-wait shadow, wave0-only epilogue (reduce+update) with cell state and
// bias in registers, 2 barriers/step, explicit s_waitcnt before arrival.

typedef __bf16 bf16_t;
typedef bf16_t b16x8 __attribute__((ext_vector_type(8)));
typedef short  s16x8 __attribute__((ext_vector_type(8)));
typedef float  f32x4 __attribute__((ext_vector_type(4)));

#define TQ 512
#define IQ 256
#define HQ 1024

union U8 { b16x8 b; s16x8 s; unsigned short u[8]; unsigned long long q[2]; };

__device__ __forceinline__ float bf2f(unsigned short s) {
    return __uint_as_float(((unsigned)s) << 16);
}
__device__ __forceinline__ unsigned short f2bf(float f) {
    unsigned u = __float_as_uint(f);
    u += 0x7fff + ((u >> 16) & 1);   // RNE
    return (unsigned short)(u >> 16);
}
__device__ __forceinline__ b16x8 cvt84(float4 a, float4 b) {
    U8 r;
    r.u[0] = f2bf(a.x); r.u[1] = f2bf(a.y); r.u[2] = f2bf(a.z); r.u[3] = f2bf(a.w);
    r.u[4] = f2bf(b.x); r.u[5] = f2bf(b.y); r.u[6] = f2bf(b.z); r.u[7] = f2bf(b.w);
    return r.b;
}
// agent-scope 16B load as 2x8B atomic loads — bypasses non-coherent L1/L2
__device__ __forceinline__ b16x8 load_h16(const unsigned short* p) {
    U8 r;
    r.q[0] = __hip_atomic_load((const unsigned long long*)p,
                               __ATOMIC_RELAXED, __HIP_MEMORY_SCOPE_AGENT);
    r.q[1] = __hip_atomic_load((const unsigned long long*)(p + 4),
                               __ATOMIC_RELAXED, __HIP_MEMORY_SCOPE_AGENT);
    return r.b;
}
__device__ __forceinline__ float sigm(float x) {
    return 1.f / (1.f + __expf(-x));
}
__device__ __forceinline__ float tanh_f(float v) {
    float x = fminf(fmaxf(v, -15.f), 15.f);
    float e = __expf(2.f * x);
    return (e - 1.f) / (e + 1.f);
}

__launch_bounds__(512, 2)
__global__ void lstm_persist(const float* __restrict__ x,
                             const float* __restrict__ Wih,
                             const float* __restrict__ Whh,
                             const float* __restrict__ bih,
                             const float* __restrict__ bhh,
                             const float* __restrict__ fcW,
                             const float* __restrict__ fcb,
                             float* __restrict__ out,
                             unsigned short* __restrict__ hbuf, // [2][4][16][1024] bf16
                             unsigned int* __restrict__ bar)    // [4*64]
{
    __shared__ float red[8 * 4 * 64 * 4];  // 32KB: per-wave partial C tiles

    const int tid  = threadIdx.x;
    const int w    = tid >> 6;        // wave 0..7
    const int lane = tid & 63;
    const int bid  = blockIdx.x;
    const int bg   = bid & 3;         // batch group (16 batches)
    const int ug   = bid >> 2;        // unit group (16 hidden units)

    const int l16  = lane & 15;
    const int quad = lane >> 4;

    // ---- one-time: load weight fragments into registers (bf16) ----
    // B^T-fragment: lane holds W[row = n_base + (lane&15)][k0 + quad*8 + j]
    b16x8 wih[4];        // x part: this wave's x-kstep
    b16x8 whh[4][4];     // h part: 4 ksteps x 4 gates
    {
        const int koff = quad * 8;
        #pragma unroll
        for (int g = 0; g < 4; ++g) {
            int row = g * HQ + ug * 16 + l16;
            const float* p = Wih + (size_t)row * IQ + w * 32 + koff;
            float4 a = *(const float4*)p;
            float4 b = *(const float4*)(p + 4);
            wih[g] = cvt84(a, b);
            #pragma unroll
            for (int j = 0; j < 4; ++j) {
                int k0 = (w * 4 + j) * 32 + koff;
                const float* q = Whh + (size_t)row * HQ + k0;
                float4 c = *(const float4*)q;
                float4 d = *(const float4*)(q + 4);
                whh[j][g] = cvt84(c, d);
            }
        }
    }

    // wave0 per-lane epilogue state: lane l owns (u = l&15, b = quad*4 + r)
    float c_st[4] = {0.f, 0.f, 0.f, 0.f};
    float bias_r[4];
    if (w == 0) {
        #pragma unroll
        for (int g = 0; g < 4; ++g) {
            int gr = g * HQ + ug * 16 + l16;
            bias_r[g] = bih[gr] + bhh[gr];
        }
    }

    unsigned int* mybar = &bar[bg * 64];

    // software-pipelined x load (step 0)
    const float* xbase = x + ((size_t)(bg * 16 + l16) * TQ) * IQ + w * 32 + quad * 8;
    float4 xa = *(const float4*)(xbase);
    float4 xb = *(const float4*)(xbase + 4);

    for (int t = 0; t < TQ; ++t) {
        const int p = t & 1;

        // ---- h-independent work: runs in the barrier-wait shadow ----
        b16x8 ax = cvt84(xa, xb);
        f32x4 acc[4];
        #pragma unroll
        for (int g = 0; g < 4; ++g) {
            f32x4 z = {0.f, 0.f, 0.f, 0.f};
            acc[g] = __builtin_amdgcn_mfma_f32_16x16x32_bf16(ax, wih[g], z, 0, 0, 0);
        }

        // ---- single-poller barrier: h(t) ready ----
        if (t && tid == 0) {
            unsigned target = 64u * (unsigned)t;
            while (__hip_atomic_load(mybar, __ATOMIC_RELAXED,
                                     __HIP_MEMORY_SCOPE_AGENT) < target)
                __builtin_amdgcn_s_sleep(1);
        }
        __syncthreads();   // B1: release + red[] free for rewrite
        asm volatile("" ::: "memory");

        // ---- h A-fragments + h MFMAs ----
        const unsigned short* hread = hbuf + ((size_t)p * 4 + bg) * (16 * HQ);
        b16x8 ah[4];
        #pragma unroll
        for (int j = 0; j < 4; ++j)
            ah[j] = load_h16(hread + (size_t)l16 * HQ + (w * 4 + j) * 32 + quad * 8);
        #pragma unroll
        for (int j = 0; j < 4; ++j) {
            #pragma unroll
            for (int g = 0; g < 4; ++g)
                acc[g] = __builtin_amdgcn_mfma_f32_16x16x32_bf16(ah[j], whh[j][g], acc[g], 0, 0, 0);
        }

        // ---- write per-wave partials ----
        #pragma unroll
        for (int g = 0; g < 4; ++g)
            *(f32x4*)&red[((w * 4 + g) * 64 + lane) * 4] = acc[g];
        __syncthreads();   // B2

        // prefetch x(t+1) — overlaps wave0's epilogue
        {
            size_t nt = (t + 1 < TQ) ? (size_t)(t + 1) * IQ : (size_t)t * IQ;
            xa = *(const float4*)(xbase + nt);
            xb = *(const float4*)(xbase + nt + 4);
        }

        // ---- wave0-only epilogue: reduce, update, store h, arrive ----
        if (w == 0) {
            f32x4 gv[4];
            #pragma unroll
            for (int g = 0; g < 4; ++g) {
                f32x4 s = *(const f32x4*)&red[((0 * 4 + g) * 64 + lane) * 4];
                #pragma unroll
                for (int ww = 1; ww < 8; ++ww)
                    s += *(const f32x4*)&red[((ww * 4 + g) * 64 + lane) * 4];
                gv[g] = s;
            }
            unsigned short* hw = hbuf + ((size_t)(p ^ 1) * 4 + bg) * (16 * HQ)
                               + (size_t)ug * 16 + l16;
            #pragma unroll
            for (int r = 0; r < 4; ++r) {
                float gi = gv[0][r] + bias_r[0];
                float gf = gv[1][r] + bias_r[1];
                float gg = gv[2][r] + bias_r[2];
                float go = gv[3][r] + bias_r[3];
                float i_s = sigm(gi);
                float f_s = sigm(gf);
                float g_t = tanh_f(gg);
                float o_s = sigm(go);
                float c = f_s * c_st[r] + i_s * g_t;
                c_st[r] = c;
                float h = o_s * tanh_f(c);
                int b = quad * 4 + r;
                __hip_atomic_store(hw + (size_t)b * HQ, f2bf(h),
                                   __ATOMIC_RELAXED, __HIP_MEMORY_SCOPE_AGENT);
            }
            __builtin_amdgcn_s_waitcnt(0);   // drain h stores to device-visible
            if (tid == 0)
                __hip_atomic_fetch_add(mybar, 1u, __ATOMIC_RELAXED,
                                       __HIP_MEMORY_SCOPE_AGENT);
        }
    }

    // ---- final projection: out = tanh(h_T) @ fcW^T + fcb (blocks 0..3) ----
    if (bid < 4) {
        if (tid == 0) {
            unsigned target = 64u * (unsigned)TQ;
            while (__hip_atomic_load(mybar, __ATOMIC_RELAXED,
                                     __HIP_MEMORY_SCOPE_AGENT) < target)
                __builtin_amdgcn_s_sleep(1);
        }
        __syncthreads();
        const unsigned short* hl = hbuf + (size_t)bg * (16 * HQ); // T even -> buf0
        float fb = fcb[0];
        #pragma unroll
        for (int r = 0; r < 2; ++r) {
            int b = w * 2 + r;
            float s = 0.f;
            #pragma unroll
            for (int j = 0; j < 16; ++j) {
                int u = j * 64 + lane;
                unsigned short hv = __hip_atomic_load(hl + b * HQ + u,
                                                      __ATOMIC_RELAXED,
                                                      __HIP_MEMORY_SCOPE_AGENT);
                s += tanh_f(bf2f(hv)) * fcW[u];
            }
            #pragma unroll
            for (int off = 32; off > 0; off >>= 1)
                s += __shfl_down(s, off);
            if (lane == 0) out[bg * 16 + b] = s + fb;
        }
    }
}

extern "C" void kernel_launch(void* const* d_in, const int* in_sizes, int n_in,
                              void* d_out, int out_size, void* d_ws, size_t ws_size,
                              hipStream_t stream) {
    (void)in_sizes; (void)n_in; (void)out_size; (void)ws_size;
    const float* x   = (const float*)d_in[0];
    const float* Wih = (const float*)d_in[1];
    const float* Whh = (const float*)d_in[2];
    const float* bih = (const float*)d_in[3];
    const float* bhh = (const float*)d_in[4];
    const float* fcW = (const float*)d_in[5];
    const float* fcb = (const float*)d_in[6];
    float* out = (float*)d_out;

    unsigned short* hbuf = (unsigned short*)d_ws;                       // 262144 B
    unsigned int*   bar  = (unsigned int*)((char*)d_ws + 262144);       // 1024 B

    hipMemsetAsync(d_ws, 0, 262144 + 1024, stream);

    void* args[] = { &x, &Wih, &Whh, &bih, &bhh, &fcW, &fcb, &out, &hbuf, &bar };
    hipLaunchCooperativeKernel(reinterpret_cast<void*>(lstm_persist),
                               dim3(256), dim3(512), args, 0, stream);
}

// Round 4
// 2374.923 us; speedup vs baseline: 3.9440x; 1.0365x over previous
//
#include <hip/hip_runtime.h>
#include <hip/hip_bf16.h>

// LSTM: B=64, T=512, I=256, H=1024, O=1.
// Persistent cooperative kernel: 256 blocks = 4 batch-groups x 64 unit-groups.
// R4: dataflow sync. 64 per-producer flags per batch-group (plain relaxed
// agent stores, 64B apart — no atomic RMW serialization). Each wave waits
// only on the 8 producer blocks covering its K-slice. One __syncthreads per
// step with double-buffered partial-sum LDS. Producer: h stores -> vmcnt(0)
// -> flag store (wave0 lane0).

typedef __bf16 bf16_t;
typedef bf16_t b16x8 __attribute__((ext_vector_type(8)));
typedef float  f32x4 __attribute__((ext_vector_type(4)));

#define TQ 512
#define IQ 256
#define HQ 1024

union U8 { b16x8 b; unsigned long long q[2]; unsigned short u[8]; };

__device__ __forceinline__ float bf2f(unsigned short s) {
    return __uint_as_float(((unsigned)s) << 16);
}
__device__ __forceinline__ unsigned short f2bf(float f) {
    unsigned u = __float_as_uint(f);
    u += 0x7fff + ((u >> 16) & 1);   // RNE
    return (unsigned short)(u >> 16);
}
__device__ __forceinline__ b16x8 cvt84(float4 a, float4 b) {
    U8 r;
    r.u[0] = f2bf(a.x); r.u[1] = f2bf(a.y); r.u[2] = f2bf(a.z); r.u[3] = f2bf(a.w);
    r.u[4] = f2bf(b.x); r.u[5] = f2bf(b.y); r.u[6] = f2bf(b.z); r.u[7] = f2bf(b.w);
    return r.b;
}
// agent-scope 16B load as 2x8B atomic loads — bypasses non-coherent L1/L2
__device__ __forceinline__ b16x8 load_h16(const unsigned short* p) {
    U8 r;
    r.q[0] = __hip_atomic_load((const unsigned long long*)p,
                               __ATOMIC_RELAXED, __HIP_MEMORY_SCOPE_AGENT);
    r.q[1] = __hip_atomic_load((const unsigned long long*)(p + 4),
                               __ATOMIC_RELAXED, __HIP_MEMORY_SCOPE_AGENT);
    return r.b;
}
__device__ __forceinline__ float sigm(float x) {
    return 1.f / (1.f + __expf(-x));
}
__device__ __forceinline__ float tanh_f(float v) {
    float x = fminf(fmaxf(v, -15.f), 15.f);
    float e = __expf(2.f * x);
    return (e - 1.f) / (e + 1.f);
}

__launch_bounds__(512, 2)
__global__ void lstm_persist(const float* __restrict__ x,
                             const float* __restrict__ Wih,
                             const float* __restrict__ Whh,
                             const float* __restrict__ bih,
                             const float* __restrict__ bhh,
                             const float* __restrict__ fcW,
                             const float* __restrict__ fcb,
                             float* __restrict__ out,
                             unsigned short* __restrict__ hbuf, // [2][4][16][1024] bf16
                             unsigned int* __restrict__ bar)    // [4][64] flags, 64B apart
{
    __shared__ float red[2 * 8192];   // 64KB: double-buffered per-wave partials

    const int tid  = threadIdx.x;
    const int w    = tid >> 6;        // wave 0..7
    const int lane = tid & 63;
    const int bid  = blockIdx.x;
    const int bg   = bid & 3;         // batch group (16 batches)
    const int ug   = bid >> 2;        // unit group (16 hidden units)

    const int l16  = lane & 15;
    const int quad = lane >> 4;

    // ---- one-time: load weight fragments into registers (bf16) ----
    b16x8 wih[4];        // x part: this wave's x-kstep
    b16x8 whh[4][4];     // h part: 4 ksteps x 4 gates
    {
        const int koff = quad * 8;
        #pragma unroll
        for (int g = 0; g < 4; ++g) {
            int row = g * HQ + ug * 16 + l16;
            const float* p = Wih + (size_t)row * IQ + w * 32 + koff;
            float4 a = *(const float4*)p;
            float4 b = *(const float4*)(p + 4);
            wih[g] = cvt84(a, b);
            #pragma unroll
            for (int j = 0; j < 4; ++j) {
                int k0 = (w * 4 + j) * 32 + koff;
                const float* q = Whh + (size_t)row * HQ + k0;
                float4 c = *(const float4*)q;
                float4 d = *(const float4*)(q + 4);
                whh[j][g] = cvt84(c, d);
            }
        }
    }

    // wave0 epilogue state: lane owns (u = l16, batches quad*4 + r)
    float c_st[4] = {0.f, 0.f, 0.f, 0.f};
    float bias_r[4];
    if (w == 0) {
        #pragma unroll
        for (int g = 0; g < 4; ++g) {
            int gr = g * HQ + ug * 16 + l16;
            bias_r[g] = bih[gr] + bhh[gr];
        }
    }

    // flags for this batch group: fl[j*16] is producer j's step counter
    unsigned int* fl = bar + (size_t)bg * 1024;           // 64 x 64B
    const unsigned int* myfl = fl + (size_t)(w * 8 + (lane & 7)) * 16;

    // software-pipelined x load (step 0)
    const float* xbase = x + ((size_t)(bg * 16 + l16) * TQ) * IQ + w * 32 + quad * 8;
    float4 xa = *(const float4*)(xbase);
    float4 xb = *(const float4*)(xbase + 4);

    for (int t = 0; t < TQ; ++t) {
        const int p = t & 1;

        // ---- h-independent shadow work ----
        b16x8 ax = cvt84(xa, xb);
        f32x4 acc[4];
        #pragma unroll
        for (int g = 0; g < 4; ++g) {
            f32x4 z = {0.f, 0.f, 0.f, 0.f};
            acc[g] = __builtin_amdgcn_mfma_f32_16x16x32_bf16(ax, wih[g], z, 0, 0, 0);
        }

        // ---- per-wave wait on this K-slice's 8 producers ----
        if (t) {
            unsigned tv = (unsigned)t;
            unsigned v = __hip_atomic_load(myfl, __ATOMIC_RELAXED,
                                           __HIP_MEMORY_SCOPE_AGENT);
            while (!__all(v >= tv))
                v = __hip_atomic_load(myfl, __ATOMIC_RELAXED,
                                      __HIP_MEMORY_SCOPE_AGENT);
        }

        // ---- h A-fragments + h MFMAs ----
        const unsigned short* hread = hbuf + ((size_t)p * 4 + bg) * (16 * HQ);
        b16x8 ah[4];
        #pragma unroll
        for (int j = 0; j < 4; ++j)
            ah[j] = load_h16(hread + (size_t)l16 * HQ + (w * 4 + j) * 32 + quad * 8);
        #pragma unroll
        for (int j = 0; j < 4; ++j) {
            #pragma unroll
            for (int g = 0; g < 4; ++g)
                acc[g] = __builtin_amdgcn_mfma_f32_16x16x32_bf16(ah[j], whh[j][g], acc[g], 0, 0, 0);
        }

        // ---- write per-wave partials (double-buffered) ----
        float* rb = &red[p * 8192];
        #pragma unroll
        for (int g = 0; g < 4; ++g)
            *(f32x4*)&rb[((w * 4 + g) * 64 + lane) * 4] = acc[g];
        __syncthreads();   // the single per-step block barrier

        if (w == 0) {
            // ---- reduce 8 K-partials ----
            f32x4 gv[4];
            #pragma unroll
            for (int g = 0; g < 4; ++g) {
                f32x4 s = *(const f32x4*)&rb[((0 * 4 + g) * 64 + lane) * 4];
                #pragma unroll
                for (int ww = 1; ww < 8; ++ww)
                    s += *(const f32x4*)&rb[((ww * 4 + g) * 64 + lane) * 4];
                gv[g] = s;
            }
            // ---- nonlinearities + h stores, interleaved per batch row ----
            unsigned short* hw = hbuf + ((size_t)(p ^ 1) * 4 + bg) * (16 * HQ)
                               + (size_t)ug * 16 + l16;
            #pragma unroll
            for (int r = 0; r < 4; ++r) {
                float gi = gv[0][r] + bias_r[0];
                float gf = gv[1][r] + bias_r[1];
                float gg = gv[2][r] + bias_r[2];
                float go = gv[3][r] + bias_r[3];
                float i_s = sigm(gi);
                float f_s = sigm(gf);
                float g_t = tanh_f(gg);
                float o_s = sigm(go);
                float c = f_s * c_st[r] + i_s * g_t;
                c_st[r] = c;
                float h = o_s * tanh_f(c);
                int b = quad * 4 + r;
                __hip_atomic_store(hw + (size_t)b * HQ, f2bf(h),
                                   __ATOMIC_RELAXED, __HIP_MEMORY_SCOPE_AGENT);
            }
            // drain h stores to the device-visible point, then signal
            asm volatile("s_waitcnt vmcnt(0)" ::: "memory");
            if (lane == 0)
                __hip_atomic_store(fl + (size_t)ug * 16, (unsigned)(t + 1),
                                   __ATOMIC_RELAXED, __HIP_MEMORY_SCOPE_AGENT);
            // x prefetch after the signal (keeps it out of the drain)
            size_t nt = (t + 1 < TQ) ? (size_t)(t + 1) * IQ : (size_t)t * IQ;
            xa = *(const float4*)(xbase + nt);
            xb = *(const float4*)(xbase + nt + 4);
        } else {
            // x prefetch overlaps wave0's epilogue
            size_t nt = (t + 1 < TQ) ? (size_t)(t + 1) * IQ : (size_t)t * IQ;
            xa = *(const float4*)(xbase + nt);
            xb = *(const float4*)(xbase + nt + 4);
        }
    }

    // ---- final projection: out = tanh(h_T) @ fcW^T + fcb (blocks 0..3) ----
    if (bid < 4) {
        if (w == 0) {
            const unsigned int* pf = fl + (size_t)lane * 16;
            unsigned v = __hip_atomic_load(pf, __ATOMIC_RELAXED,
                                           __HIP_MEMORY_SCOPE_AGENT);
            while (!__all(v >= (unsigned)TQ))
                v = __hip_atomic_load(pf, __ATOMIC_RELAXED,
                                      __HIP_MEMORY_SCOPE_AGENT);
        }
        __syncthreads();
        const unsigned short* hl = hbuf + (size_t)bg * (16 * HQ); // T even -> buf0
        float fb = fcb[0];
        #pragma unroll
        for (int r = 0; r < 2; ++r) {
            int b = w * 2 + r;
            float s = 0.f;
            #pragma unroll
            for (int j = 0; j < 16; ++j) {
                int u = j * 64 + lane;
                unsigned short hv = __hip_atomic_load(hl + b * HQ + u,
                                                      __ATOMIC_RELAXED,
                                                      __HIP_MEMORY_SCOPE_AGENT);
                s += tanh_f(bf2f(hv)) * fcW[u];
            }
            #pragma unroll
            for (int off = 32; off > 0; off >>= 1)
                s += __shfl_down(s, off);
            if (lane == 0) out[bg * 16 + b] = s + fb;
        }
    }
}

extern "C" void kernel_launch(void* const* d_in, const int* in_sizes, int n_in,
                              void* d_out, int out_size, void* d_ws, size_t ws_size,
                              hipStream_t stream) {
    (void)in_sizes; (void)n_in; (void)out_size; (void)ws_size;
    const float* x   = (const float*)d_in[0];
    const float* Wih = (const float*)d_in[1];
    const float* Whh = (const float*)d_in[2];
    const float* bih = (const float*)d_in[3];
    const float* bhh = (const float*)d_in[4];
    const float* fcW = (const float*)d_in[5];
    const float* fcb = (const float*)d_in[6];
    float* out = (float*)d_out;

    unsigned short* hbuf = (unsigned short*)d_ws;                       // 262144 B
    unsigned int*   bar  = (unsigned int*)((char*)d_ws + 262144);       // 16384 B

    hipMemsetAsync(d_ws, 0, 262144 + 16384, stream);

    void* args[] = { &x, &Wih, &Whh, &bih, &bhh, &fcW, &fcb, &out, &hbuf, &bar };
    hipLaunchCooperativeKernel(reinterpret_cast<void*>(lstm_persist),
                               dim3(256), dim3(512), args, 0, stream);
}